// Round 2
// baseline (472.322 us; speedup 1.0000x reference)
//
#include <hip/hip_runtime.h>
#include <math.h>
#include <stdint.h>

#define V_N 100000
#define E_N 300000
#define D_N 128
#define EPSV 1e-5f
#define NCHUNK 391   // ceil(V_N/256)
#define MPAD 100096  // 1564 * 64
#define NBLK 1563    // ceil(V_N/64)

typedef _Float16 f16;
typedef f16 f16x8 __attribute__((ext_vector_type(8)));
typedef f16 f16x4 __attribute__((ext_vector_type(4)));
typedef f16 f16x2 __attribute__((ext_vector_type(2)));
typedef float f32x4 __attribute__((ext_vector_type(4)));

// ----------------- CSR build -----------------
__global__ __launch_bounds__(256) void k_count(const int* __restrict__ edges, int* __restrict__ deg) {
  int i = blockIdx.x * blockDim.x + threadIdx.x;
  if (i < 2 * E_N) atomicAdd(&deg[edges[i]], 1);
}

__global__ __launch_bounds__(256) void k_chunksum(const int* __restrict__ deg, int* __restrict__ csum) {
  __shared__ int red[256];
  int c = blockIdx.x, t = threadIdx.x;
  int i = c * 256 + t;
  red[t] = (i < V_N) ? deg[i] : 0;
  __syncthreads();
  for (int s = 128; s > 0; s >>= 1) {
    if (t < s) red[t] += red[t + s];
    __syncthreads();
  }
  if (t == 0) csum[c] = red[0];
}

__global__ __launch_bounds__(512) void k_scanchunks(const int* __restrict__ csum, int* __restrict__ coff) {
  __shared__ int sh[512];
  int t = threadIdx.x;
  int v = (t < NCHUNK) ? csum[t] : 0;
  sh[t] = v;
  __syncthreads();
  for (int s = 1; s < 512; s <<= 1) {
    int x = (t >= s) ? sh[t - s] : 0;
    __syncthreads();
    sh[t] += x;
    __syncthreads();
  }
  if (t < NCHUNK) coff[t] = sh[t] - v;  // exclusive
}

__global__ __launch_bounds__(256) void k_writeoff(const int* __restrict__ deg, const int* __restrict__ coff,
                                                  int* __restrict__ csr_off, float* __restrict__ dinv,
                                                  float* __restrict__ degf) {
  __shared__ int sh[256];
  int c = blockIdx.x, t = threadIdx.x;
  int i = c * 256 + t;
  int v = (i < V_N) ? deg[i] : 0;
  sh[t] = v;
  __syncthreads();
  for (int s = 1; s < 256; s <<= 1) {
    int x = (t >= s) ? sh[t - s] : 0;
    __syncthreads();
    sh[t] += x;
    __syncthreads();
  }
  int excl = sh[t] - v;
  if (i <= V_N) csr_off[i] = coff[c] + excl;
  if (i < V_N) {
    dinv[i] = 1.0f / (1.0f + (float)v);
    degf[i] = (float)v;
  }
}

__global__ __launch_bounds__(256) void k_fill(const int* __restrict__ edges, const int* __restrict__ csr_off,
                                              int* __restrict__ cursor, int* __restrict__ adj) {
  int e = blockIdx.x * blockDim.x + threadIdx.x;
  if (e >= E_N) return;
  int s = edges[2 * e], d = edges[2 * e + 1];
  int p = atomicAdd(&cursor[s], 1);
  adj[csr_off[s] + p] = d;
  int q = atomicAdd(&cursor[d], 1);
  adj[csr_off[d] + q] = s;
}

// ----------------- weight prep: Wcat[l][n][k] half, k = [W0 row | W1 row] -----------------
__global__ __launch_bounds__(256) void k_prepw(const float* __restrict__ W0, const float* __restrict__ W1,
                                               f16* __restrict__ Wc) {
  int idx = blockIdx.x * 256 + threadIdx.x;
  if (idx >= 3 * 128 * 256) return;
  int l = idx >> 15;
  int rem = idx & 32767;
  int n = rem >> 8, k = rem & 255;
  float v = (k < 128) ? W0[l * 16384 + n * 128 + k] : W1[l * 16384 + n * 128 + (k - 128)];
  Wc[idx] = (f16)v;
}

// ----------------- cast: y[v] = f16(features[v]) (layer 0 input) -----------------
__global__ __launch_bounds__(256) void k_cast(const float* __restrict__ x, f16* __restrict__ y) {
  int q = blockIdx.x * 256 + threadIdx.x;  // float4 index over V_N*128
  if (q >= V_N * 32) return;
  float4 xv = ((const float4*)x)[q];
  f16x4 h;
  h[0] = (f16)xv.x; h[1] = (f16)xv.y; h[2] = (f16)xv.z; h[3] = (f16)xv.w;
  *(f16x4*)&y[(size_t)q * 4] = h;
}

// ----------------- fused layer: gather (into LDS) + GEMM + BN stats, barrier-free --------
// Block owns 64 rows; wave w owns rows w*16..w*16+15 EXCLUSIVELY (gather writes them into
// the swizzled LDS A-tile, MFMA reads only them, epilogue writes only them). No
// __syncthreads anywhere: each wave orders its own LDS write->read with
// s_waitcnt lgkmcnt(0) + sched_barrier. B fragments are read directly from global
// (Wcat slice = 64KB, identical across all blocks -> L1/L2-hot). Stats go straight to
// 64-way-sharded global atomics after a per-wave shuffle reduction.
template <int MODE>
__global__ __launch_bounds__(256, 4) void k_layer(const f16* __restrict__ tin, const f16* __restrict__ Wc,
                                                  const float* __restrict__ b0, const float* __restrict__ b1,
                                                  const float* __restrict__ dinv, const float* __restrict__ degf,
                                                  const int* __restrict__ csr_off, const int* __restrict__ adj,
                                                  const float* __restrict__ scale, const float* __restrict__ shift,
                                                  f16* __restrict__ tout, float* __restrict__ stats) {
  __shared__ __align__(16) f16 As[64 * 256];   // 32KB; 16B chunk (r,c) at slot c^(r&7) within row
  int tid = threadIdx.x;
  int w = tid >> 6, lane = tid & 63;
  int quad = lane >> 4, l16 = lane & 15;
  int row0 = blockIdx.x * 64;
  int c0 = lane * 2;

  f16x2 scv = {}, sfv = {};
  if (MODE) {
    scv[0] = (f16)scale[c0]; scv[1] = (f16)scale[c0 + 1];
    sfv[0] = (f16)shift[c0]; sfv[1] = (f16)shift[c0 + 1];
  }
  f16x2 zero = {};

#pragma unroll 1
  for (int g = 0; g < 4; ++g) {
    int vbase = row0 + w * 16 + g * 4;
    int s[4], e[4];
#pragma unroll
    for (int i = 0; i < 4; ++i) {
      int v = vbase + i;
      s[i] = (v < V_N) ? csr_off[v] : 0;
      e[i] = (v < V_N) ? csr_off[v + 1] : 0;
    }
    // all 32 adjacency indices (clamped), then all 32 row loads -> 32 outstanding VMEM ops
    int idx[4][8];
#pragma unroll
    for (int i = 0; i < 4; ++i)
#pragma unroll
      for (int j = 0; j < 8; ++j) {
        int pp = s[i] + j;
        int cl = pp < e[i] ? pp : e[i] - 1;
        idx[i][j] = adj[cl > 0 ? cl : 0];
      }
    f16x2 h[4][8];
#pragma unroll
    for (int i = 0; i < 4; ++i)
#pragma unroll
      for (int j = 0; j < 8; ++j)
        h[i][j] = *(const f16x2*)&tin[(size_t)idx[i][j] * 128 + c0];
    f16x2 own[4];
#pragma unroll
    for (int i = 0; i < 4; ++i) {
      int v = vbase + i;
      own[i] = (v < V_N) ? *(const f16x2*)&tin[(size_t)v * 128 + c0] : zero;
    }
#pragma unroll
    for (int i = 0; i < 4; ++i) {
      float a0, a1;
      {
#pragma unroll
        for (int j = 0; j < 8; ++j) {
          f16x2 u = h[i][j];
          if (MODE) u = __builtin_elementwise_max(scv * u + sfv, zero);
          h[i][j] = (s[i] + j < e[i]) ? u : zero;
        }
        f16x2 t01 = h[i][0] + h[i][1], t23 = h[i][2] + h[i][3];
        f16x2 t45 = h[i][4] + h[i][5], t67 = h[i][6] + h[i][7];
        f16x2 sum = (t01 + t23) + (t45 + t67);
        a0 = (float)sum[0];
        a1 = (float)sum[1];
      }
      // tail for deg > 8 (wave-uniform trip count)
      for (int p = s[i] + 8; p < e[i]; p += 8) {
        int id2[8];
#pragma unroll
        for (int j = 0; j < 8; ++j) {
          int pp = p + j;
          id2[j] = adj[pp < e[i] ? pp : e[i] - 1];
        }
        f16x2 gg[8];
#pragma unroll
        for (int j = 0; j < 8; ++j) gg[j] = *(const f16x2*)&tin[(size_t)id2[j] * 128 + c0];
#pragma unroll
        for (int j = 0; j < 8; ++j) {
          f16x2 u = gg[j];
          if (MODE) u = __builtin_elementwise_max(scv * u + sfv, zero);
          gg[j] = (p + j < e[i]) ? u : zero;
        }
        f16x2 t01 = gg[0] + gg[1], t23 = gg[2] + gg[3];
        f16x2 t45 = gg[4] + gg[5], t67 = gg[6] + gg[7];
        f16x2 sum = (t01 + t23) + (t45 + t67);
        a0 += (float)sum[0];
        a1 += (float)sum[1];
      }
      f16x2 o;
      o[0] = (f16)a0;
      o[1] = (f16)a1;
      f16x2 yo = own[i];
      if (MODE) yo = __builtin_elementwise_max(scv * yo + sfv, zero);
      if (vbase + i >= V_N) { yo = zero; o = zero; }
      int r = w * 16 + g * 4 + i;   // local row 0..63
      int cy = c0 >> 3;             // y-half chunk 0..15
      int cx = 16 + cy;             // xa-half chunk 16..31
      *(f16x2*)&As[r * 256 + ((cy ^ (r & 7)) << 3) + (c0 & 7)] = yo;
      *(f16x2*)&As[r * 256 + ((cx ^ (r & 7)) << 3) + (c0 & 7)] = o;
    }
  }
  // per-wave LDS write->read fence (rule #18): drain ds_writes, pin the scheduler
  asm volatile("s_waitcnt lgkmcnt(0)" ::: "memory");
  __builtin_amdgcn_sched_barrier(0);

  // MFMA: this wave's 16 rows only; B fragments straight from global (L1/L2-hot)
  f32x4 acc[8] = {};
  int rr = w * 16 + l16;
  const f16* arow = &As[rr * 256];
#pragma unroll
  for (int kc = 0; kc < 4; ++kc) {
#pragma unroll
    for (int ks = 0; ks < 2; ++ks) {
      int ca = kc * 8 + ks * 4 + quad;  // A chunk index 0..31
      f16x8 af = *(const f16x8*)&arow[((ca ^ (rr & 7)) << 3)];
#pragma unroll
      for (int ni = 0; ni < 8; ++ni) {
        f16x8 bf = *(const f16x8*)&Wc[(size_t)(ni * 16 + l16) * 256 + kc * 64 + (ks * 4 + quad) * 8];
        acc[ni] = __builtin_amdgcn_mfma_f32_16x16x32_f16(af, bf, acc[ni], 0, 0, 0);
      }
    }
  }

  float b0c[8], b1c[8];
#pragma unroll
  for (int ni = 0; ni < 8; ++ni) {
    b0c[ni] = b0[ni * 16 + l16];
    b1c[ni] = b1[ni * 16 + l16];
  }
  float csum[8] = {}, csq[8] = {};
  // C/D layout: col = l16, row = quad*4 + reg
#pragma unroll
  for (int reg = 0; reg < 4; ++reg) {
    int v = row0 + w * 16 + quad * 4 + reg;
    if (v < V_N) {
      float dv = dinv[v], gf = degf[v];
#pragma unroll
      for (int ni = 0; ni < 8; ++ni) {
        float tv = dv * (acc[ni][reg] + b0c[ni] + gf * b1c[ni]);
        tout[(size_t)v * 128 + ni * 16 + l16] = (f16)tv;
        csum[ni] += tv;
        csq[ni] += tv * tv;
      }
    }
  }
#pragma unroll
  for (int ni = 0; ni < 8; ++ni) {
    csum[ni] += __shfl_xor(csum[ni], 16);
    csum[ni] += __shfl_xor(csum[ni], 32);
    csq[ni] += __shfl_xor(csq[ni], 16);
    csq[ni] += __shfl_xor(csq[ni], 32);
  }
  if (quad == 0) {
    float* sh = &stats[(blockIdx.x & 63) * 256];
#pragma unroll
    for (int ni = 0; ni < 8; ++ni) {
      atomicAdd(&sh[ni * 16 + l16], csum[ni]);
      atomicAdd(&sh[128 + ni * 16 + l16], csq[ni]);
    }
  }
}

__global__ void k_finalize(float* __restrict__ stats, const float* __restrict__ gamma,
                           const float* __restrict__ beta, float* __restrict__ scale,
                           float* __restrict__ shift) {
  int d = threadIdx.x;  // 128
  float s = 0.f, sq = 0.f;
#pragma unroll 8
  for (int h = 0; h < 64; ++h) {
    s += stats[h * 256 + d];
    sq += stats[h * 256 + 128 + d];
    stats[h * 256 + d] = 0.f;        // re-zero for next layer (single block -> race-free)
    stats[h * 256 + 128 + d] = 0.f;
  }
  float mu = s * (1.0f / V_N);
  float var = sq * (1.0f / V_N) - mu * mu;
  float scv = gamma[d] * rsqrtf(var + EPSV);
  scale[d] = scv;
  shift[d] = beta[d] - mu * scv;
}

// ----------------- final: out = relu(scale*t + shift + features) -----------------
__global__ __launch_bounds__(256) void k_final(const f16* __restrict__ t, const float* __restrict__ feat,
                                               const float* __restrict__ scale, const float* __restrict__ shift,
                                               float* __restrict__ out) {
  int q = blockIdx.x * 256 + threadIdx.x;  // float4 index
  if (q >= V_N * 32) return;
  int c4 = q & 31;
  f16x4 tv = *(const f16x4*)&t[(size_t)q * 4];
  float4 fv = ((const float4*)feat)[q];
  float4 sc = ((const float4*)scale)[c4];
  float4 sf = ((const float4*)shift)[c4];
  float4 o;
  o.x = fmaxf(sc.x * (float)tv[0] + sf.x + fv.x, 0.f);
  o.y = fmaxf(sc.y * (float)tv[1] + sf.y + fv.y, 0.f);
  o.z = fmaxf(sc.z * (float)tv[2] + sf.z + fv.z, 0.f);
  o.w = fmaxf(sc.w * (float)tv[3] + sf.w + fv.w, 0.f);
  ((float4*)out)[q] = o;
}

extern "C" void kernel_launch(void* const* d_in, const int* in_sizes, int n_in,
                              void* d_out, int out_size, void* d_ws, size_t ws_size,
                              hipStream_t stream) {
  const float* features = (const float*)d_in[0];
  const int* edges = (const int*)d_in[1];
  const float* W0 = (const float*)d_in[2];
  const float* b0 = (const float*)d_in[3];
  const float* W1 = (const float*)d_in[4];
  const float* b1 = (const float*)d_in[5];
  const float* gamma = (const float*)d_in[6];
  const float* beta = (const float*)d_in[7];
  float* out = (float*)d_out;

  char* ws = (char*)d_ws;
  size_t off = 0;
  auto alloc = [&](size_t bytes) -> void* {
    void* p = ws + off;
    off = (off + bytes + 255) & ~(size_t)255;
    return p;
  };
  int* deg = (int*)alloc((size_t)V_N * 4);
  int* csr_off = (int*)alloc((size_t)(V_N + 1) * 4);
  int* adj = (int*)alloc((size_t)2 * E_N * 4);
  float* dinv = (float*)alloc((size_t)V_N * 4);
  float* degf = (float*)alloc((size_t)V_N * 4);
  int* csum = (int*)alloc(512 * 4);
  int* coff = (int*)alloc(512 * 4);
  float* stats = (float*)alloc(64 * 256 * 4);
  float* scale = (float*)alloc(128 * 4);
  float* shift = (float*)alloc(128 * 4);
  f16* y = (f16*)alloc((size_t)MPAD * 128 * 2);
  f16* tA = (f16*)alloc((size_t)MPAD * 128 * 2);
  f16* tB = (f16*)alloc((size_t)MPAD * 128 * 2);
  f16* Wcat = (f16*)alloc((size_t)3 * 128 * 256 * 2);

  // CSR + dinv/degf
  hipMemsetAsync(deg, 0, (size_t)V_N * 4, stream);
  k_count<<<(2 * E_N + 255) / 256, 256, 0, stream>>>(edges, deg);
  k_chunksum<<<NCHUNK, 256, 0, stream>>>(deg, csum);
  k_scanchunks<<<1, 512, 0, stream>>>(csum, coff);
  k_writeoff<<<NCHUNK, 256, 0, stream>>>(deg, coff, csr_off, dinv, degf);
  hipMemsetAsync(deg, 0, (size_t)V_N * 4, stream);
  k_fill<<<(E_N + 255) / 256, 256, 0, stream>>>(edges, csr_off, deg, adj);
  k_prepw<<<384, 256, 0, stream>>>(W0, W1, Wcat);
  k_cast<<<12500, 256, 0, stream>>>(features, y);
  hipMemsetAsync(stats, 0, (size_t)64 * 256 * 4, stream);

  // layer 0: in = y (cast features), out = tA
  k_layer<0><<<NBLK, 256, 0, stream>>>(y, Wcat, b0, b1, dinv, degf, csr_off, adj,
                                       scale, shift, tA, stats);
  k_finalize<<<1, 128, 0, stream>>>(stats, gamma, beta, scale, shift);
  // layer 1: in = tA (+scale/shift), out = tB
  k_layer<1><<<NBLK, 256, 0, stream>>>(tA, Wcat + (size_t)1 * 128 * 256, b0 + D_N, b1 + D_N,
                                       dinv, degf, csr_off, adj, scale, shift, tB, stats);
  k_finalize<<<1, 128, 0, stream>>>(stats, gamma + D_N, beta + D_N, scale, shift);
  // layer 2: in = tB, out = tA
  k_layer<1><<<NBLK, 256, 0, stream>>>(tB, Wcat + (size_t)2 * 128 * 256, b0 + 2 * D_N, b1 + 2 * D_N,
                                       dinv, degf, csr_off, adj, scale, shift, tA, stats);
  k_finalize<<<1, 128, 0, stream>>>(stats, gamma + 2 * D_N, beta + 2 * D_N, scale, shift);

  k_final<<<12500, 256, 0, stream>>>(tA, features, scale, shift, out);
}

// Round 3
// 363.217 us; speedup vs baseline: 1.3004x; 1.3004x over previous
//
#include <hip/hip_runtime.h>
#include <math.h>
#include <stdint.h>

#define V_N 100000
#define E_N 300000
#define D_N 128
#define EPSV 1e-5f
#define NCHUNK 391   // ceil(V_N/256)
#define MPAD 100096  // 1564 * 64

typedef _Float16 f16;
typedef f16 f16x8 __attribute__((ext_vector_type(8)));
typedef f16 f16x4 __attribute__((ext_vector_type(4)));
typedef f16 f16x2 __attribute__((ext_vector_type(2)));
typedef float f32x4 __attribute__((ext_vector_type(4)));

// async global->LDS, 16B per lane; lds base must be wave-uniform
#define GLD(g, l) __builtin_amdgcn_global_load_lds( \
    (__attribute__((address_space(1))) void*)(g),   \
    (__attribute__((address_space(3))) void*)(l), 16, 0, 0)

// ----------------- CSR build -----------------
__global__ __launch_bounds__(256) void k_count(const int* __restrict__ edges, int* __restrict__ deg) {
  int i = blockIdx.x * blockDim.x + threadIdx.x;
  if (i < 2 * E_N) atomicAdd(&deg[edges[i]], 1);
}

__global__ __launch_bounds__(256) void k_chunksum(const int* __restrict__ deg, int* __restrict__ csum) {
  __shared__ int red[256];
  int c = blockIdx.x, t = threadIdx.x;
  int i = c * 256 + t;
  red[t] = (i < V_N) ? deg[i] : 0;
  __syncthreads();
  for (int s = 128; s > 0; s >>= 1) {
    if (t < s) red[t] += red[t + s];
    __syncthreads();
  }
  if (t == 0) csum[c] = red[0];
}

__global__ __launch_bounds__(512) void k_scanchunks(const int* __restrict__ csum, int* __restrict__ coff) {
  __shared__ int sh[512];
  int t = threadIdx.x;
  int v = (t < NCHUNK) ? csum[t] : 0;
  sh[t] = v;
  __syncthreads();
  for (int s = 1; s < 512; s <<= 1) {
    int x = (t >= s) ? sh[t - s] : 0;
    __syncthreads();
    sh[t] += x;
    __syncthreads();
  }
  if (t < NCHUNK) coff[t] = sh[t] - v;  // exclusive
}

__global__ __launch_bounds__(256) void k_writeoff(const int* __restrict__ deg, const int* __restrict__ coff,
                                                  int* __restrict__ csr_off, float* __restrict__ dinv,
                                                  float* __restrict__ degf) {
  __shared__ int sh[256];
  int c = blockIdx.x, t = threadIdx.x;
  int i = c * 256 + t;
  int v = (i < V_N) ? deg[i] : 0;
  sh[t] = v;
  __syncthreads();
  for (int s = 1; s < 256; s <<= 1) {
    int x = (t >= s) ? sh[t - s] : 0;
    __syncthreads();
    sh[t] += x;
    __syncthreads();
  }
  int excl = sh[t] - v;
  if (i <= V_N) csr_off[i] = coff[c] + excl;
  if (i < V_N) {
    dinv[i] = 1.0f / (1.0f + (float)v);
    degf[i] = (float)v;
  }
}

// fills CSR adj AND the ELL8 fast-path array (first 8 neighbors at adjell[v*8+j]).
// Slots j >= deg stay uninitialized (workspace garbage) -> consumer clamps before use.
__global__ __launch_bounds__(256) void k_fill(const int* __restrict__ edges, const int* __restrict__ csr_off,
                                              int* __restrict__ cursor, int* __restrict__ adj,
                                              int* __restrict__ adjell) {
  int e = blockIdx.x * blockDim.x + threadIdx.x;
  if (e >= E_N) return;
  int s = edges[2 * e], d = edges[2 * e + 1];
  int p = atomicAdd(&cursor[s], 1);
  adj[csr_off[s] + p] = d;
  if (p < 8) adjell[s * 8 + p] = d;
  int q = atomicAdd(&cursor[d], 1);
  adj[csr_off[d] + q] = s;
  if (q < 8) adjell[d * 8 + q] = s;
}

// ----------------- merged prep: Wcat[l][n][k] half (k=[W0 row|W1 row]) + f16 cast of features --
__global__ __launch_bounds__(256) void k_prepcast(const float* __restrict__ W0, const float* __restrict__ W1,
                                                  f16* __restrict__ Wc, const float* __restrict__ x,
                                                  f16* __restrict__ y) {
  int b = blockIdx.x;
  if (b < 384) {  // 384*256 == 3*128*256 exactly
    int idx = b * 256 + threadIdx.x;
    int l = idx >> 15;
    int rem = idx & 32767;
    int n = rem >> 8, k = rem & 255;
    float v = (k < 128) ? W0[l * 16384 + n * 128 + k] : W1[l * 16384 + n * 128 + (k - 128)];
    Wc[idx] = (f16)v;
  } else {
    int q = (b - 384) * 256 + threadIdx.x;  // float4 index over V_N*128
    if (q >= V_N * 32) return;
    float4 xv = ((const float4*)x)[q];
    f16x4 h;
    h[0] = (f16)xv.x; h[1] = (f16)xv.y; h[2] = (f16)xv.z; h[3] = (f16)xv.w;
    *(f16x4*)&y[(size_t)q * 4] = h;
  }
}

// ----------------- gather: 4 vertices per wave, ELL8 fast path, packed-f16 math ----------
// MODE 0: neighbors from y (raw), write xa only.
// MODE 1: neighbors from tin with relu(scale*t+shift) on the fly; also write y_v.
// ELL8: idx-load addresses depend only on v -> deg/csr/idx loads all issue in parallel
// (2-hop chain instead of 3). Tail (deg > 8, ~11% of vertices) walks CSR as before.
// Blocks 0..63 zero the 64 stats shards. Grid: 6250 blocks x 4 waves x 4 verts = 100000.
template <int MODE>
__global__ __launch_bounds__(256) void k_gather(const f16* __restrict__ tin, f16* __restrict__ y,
                                                f16* __restrict__ xa, const int* __restrict__ deg,
                                                const int* __restrict__ csr_off,
                                                const int* __restrict__ adjell, const int* __restrict__ adj,
                                                const float* __restrict__ scale,
                                                const float* __restrict__ shift, float* __restrict__ stats) {
  if (blockIdx.x < 64) stats[blockIdx.x * 256 + threadIdx.x] = 0.f;
  int w = threadIdx.x >> 6, lane = threadIdx.x & 63;
  int vbase = (blockIdx.x * 4 + w) * 4;
  int c0 = lane * 2;
  f16x2 scv = {}, sfv = {};
  if (MODE) {
    scv[0] = (f16)scale[c0]; scv[1] = (f16)scale[c0 + 1];
    sfv[0] = (f16)shift[c0]; sfv[1] = (f16)shift[c0 + 1];
  }
  const f16* base = MODE ? tin : y;
  int dg[4], s0[4];
#pragma unroll
  for (int i = 0; i < 4; ++i) {
    dg[i] = deg[vbase + i];
    s0[i] = csr_off[vbase + i];  // only on the tail path; issues in parallel with everything
  }
  // ELL8 indices: addresses known from v alone; clamp garbage padding slots
  int idx[4][8];
#pragma unroll
  for (int i = 0; i < 4; ++i)
#pragma unroll
    for (int j = 0; j < 8; ++j) {
      int t = adjell[(vbase + i) * 8 + j];
      idx[i][j] = ((unsigned)t < (unsigned)V_N) ? t : 0;
    }
  f16x2 h[4][8];
#pragma unroll
  for (int i = 0; i < 4; ++i)
#pragma unroll
    for (int j = 0; j < 8; ++j)
      h[i][j] = *(const f16x2*)&base[(size_t)idx[i][j] * 128 + c0];
  f16x2 own[4];
  if (MODE) {
#pragma unroll
    for (int i = 0; i < 4; ++i) own[i] = *(const f16x2*)&tin[(size_t)(vbase + i) * 128 + c0];
  }
  f16x2 zero = {};
#pragma unroll
  for (int i = 0; i < 4; ++i) {
    float a0, a1;
    {
#pragma unroll
      for (int j = 0; j < 8; ++j) {
        f16x2 u = h[i][j];
        if (MODE) u = __builtin_elementwise_max(scv * u + sfv, zero);
        h[i][j] = (j < dg[i]) ? u : zero;
      }
      f16x2 t01 = h[i][0] + h[i][1], t23 = h[i][2] + h[i][3];
      f16x2 t45 = h[i][4] + h[i][5], t67 = h[i][6] + h[i][7];
      f16x2 sum = (t01 + t23) + (t45 + t67);
      a0 = (float)sum[0];
      a1 = (float)sum[1];
    }
    // tail for deg > 8 (wave-uniform trip count; P ~ 11%), via CSR
    for (int p = 8; p < dg[i]; p += 8) {
      int id2[8];
#pragma unroll
      for (int j = 0; j < 8; ++j) {
        int pp = p + j;
        id2[j] = adj[s0[i] + (pp < dg[i] ? pp : dg[i] - 1)];
      }
      f16x2 g[8];
#pragma unroll
      for (int j = 0; j < 8; ++j) g[j] = *(const f16x2*)&base[(size_t)id2[j] * 128 + c0];
#pragma unroll
      for (int j = 0; j < 8; ++j) {
        f16x2 u = g[j];
        if (MODE) u = __builtin_elementwise_max(scv * u + sfv, zero);
        g[j] = (p + j < dg[i]) ? u : zero;
      }
      f16x2 t01 = g[0] + g[1], t23 = g[2] + g[3];
      f16x2 t45 = g[4] + g[5], t67 = g[6] + g[7];
      f16x2 sum = (t01 + t23) + (t45 + t67);
      a0 += (float)sum[0];
      a1 += (float)sum[1];
    }
    f16x2 o;
    o[0] = (f16)a0;
    o[1] = (f16)a1;
    *(f16x2*)&xa[(size_t)(vbase + i) * 128 + c0] = o;
    if (MODE) {
      f16x2 yv = __builtin_elementwise_max(scv * own[i] + sfv, zero);
      *(f16x2*)&y[(size_t)(vbase + i) * 128 + c0] = yv;
    }
  }
}

// ----------------- fused GEMM: t = dinv * ([y|xa] @ Wcat^T + b0 + deg*b1); + BN stats -----
// 64 rows x 128 cols per block (1564 blocks), K=256 in 4 chunks of 64 halves.
// XOR-swizzled LDS (16B chunks), global_load_lds staging. t written as f16.
__global__ __launch_bounds__(256) void k_gemm(const f16* __restrict__ y, const f16* __restrict__ xa,
                                              const f16* __restrict__ Wc,
                                              const float* __restrict__ b0, const float* __restrict__ b1,
                                              const float* __restrict__ dinv, const float* __restrict__ degf,
                                              f16* __restrict__ tbuf, float* __restrict__ stats) {
  __shared__ __align__(16) f16 As[64 * 64];    // 512 x 16B chunks, chunk (r,c) at slot r*8 + (c^(r&7))
  __shared__ __align__(16) f16 Bs[128 * 64];   // 1024 x 16B chunks
  __shared__ float sstat[256];
  int tid = threadIdx.x;
  int w = tid >> 6, lane = tid & 63;
  int quad = lane >> 4, l16 = lane & 15;
  int row0 = blockIdx.x * 64;
  f32x4 acc[8] = {};
  sstat[tid] = 0.f;  // zeroed here; first __syncthreads below makes it visible

  for (int kc = 0; kc < 4; ++kc) {
    const f16* Abase = (kc < 2) ? y : xa;
    int koff = (kc & 1) * 64;
    // stage A: 512 chunks, 2 wave-instructions per wave
#pragma unroll
    for (int i = 0; i < 2; ++i) {
      int s = (w * 2 + i) * 64 + lane;
      int r = s >> 3, c = (s & 7) ^ (r & 7);
      GLD(Abase + (size_t)(row0 + r) * 128 + koff + c * 8, &As[(w * 2 + i) * 512]);
    }
    // stage B: 1024 chunks, 4 per wave
#pragma unroll
    for (int i = 0; i < 4; ++i) {
      int s = (w * 4 + i) * 64 + lane;
      int r = s >> 3, c = (s & 7) ^ (r & 7);
      GLD(Wc + (size_t)r * 256 + kc * 64 + c * 8, &Bs[(w * 4 + i) * 512]);
    }
    __syncthreads();  // drains vmcnt (global_load_lds) + barrier
#pragma unroll
    for (int ks = 0; ks < 2; ++ks) {
      int cc = ks * 4 + quad;
      int rr = w * 16 + l16;
      f16x8 af = *(const f16x8*)&As[(rr * 8 + (cc ^ (rr & 7))) * 8];
#pragma unroll
      for (int ni = 0; ni < 8; ++ni) {
        int rb = ni * 16 + l16;
        f16x8 bf = *(const f16x8*)&Bs[(rb * 8 + (cc ^ (rb & 7))) * 8];
        acc[ni] = __builtin_amdgcn_mfma_f32_16x16x32_f16(af, bf, acc[ni], 0, 0, 0);
      }
    }
    __syncthreads();
  }

  float b0c[8], b1c[8];
#pragma unroll
  for (int ni = 0; ni < 8; ++ni) {
    b0c[ni] = b0[ni * 16 + l16];
    b1c[ni] = b1[ni * 16 + l16];
  }
  float csum[8] = {}, csq[8] = {};
  // C/D layout: col = l16, row = quad*4 + reg
#pragma unroll
  for (int reg = 0; reg < 4; ++reg) {
    int v = row0 + w * 16 + quad * 4 + reg;
    if (v < V_N) {
      float dv = dinv[v], gf = degf[v];
#pragma unroll
      for (int ni = 0; ni < 8; ++ni) {
        float tv = dv * (acc[ni][reg] + b0c[ni] + gf * b1c[ni]);
        tbuf[(size_t)v * 128 + ni * 16 + l16] = (f16)tv;
        csum[ni] += tv;
        csq[ni] += tv * tv;
      }
    }
  }
#pragma unroll
  for (int ni = 0; ni < 8; ++ni) {
    csum[ni] += __shfl_xor(csum[ni], 16);
    csum[ni] += __shfl_xor(csum[ni], 32);
    csq[ni] += __shfl_xor(csq[ni], 16);
    csq[ni] += __shfl_xor(csq[ni], 32);
  }
  if (quad == 0) {
#pragma unroll
    for (int ni = 0; ni < 8; ++ni) {
      atomicAdd(&sstat[ni * 16 + l16], csum[ni]);
      atomicAdd(&sstat[128 + ni * 16 + l16], csq[ni]);
    }
  }
  __syncthreads();
  atomicAdd(&stats[(blockIdx.x & 63) * 256 + tid], sstat[tid]);  // 64-way sharded
}

__global__ void k_finalize(const float* __restrict__ stats, const float* __restrict__ gamma,
                           const float* __restrict__ beta, float* __restrict__ scale,
                           float* __restrict__ shift) {
  int d = threadIdx.x;  // 128
  float s = 0.f, sq = 0.f;
#pragma unroll 8
  for (int h = 0; h < 64; ++h) {
    s += stats[h * 256 + d];
    sq += stats[h * 256 + 128 + d];
  }
  float mu = s * (1.0f / V_N);
  float var = sq * (1.0f / V_N) - mu * mu;
  float scv = gamma[d] * rsqrtf(var + EPSV);
  scale[d] = scv;
  shift[d] = beta[d] - mu * scv;
}

// ----------------- final: out = relu(scale*t + shift + features) -----------------
__global__ __launch_bounds__(256) void k_final(const f16* __restrict__ t, const float* __restrict__ feat,
                                               const float* __restrict__ scale, const float* __restrict__ shift,
                                               float* __restrict__ out) {
  int q = blockIdx.x * 256 + threadIdx.x;  // float4 index
  if (q >= V_N * 32) return;
  int c4 = q & 31;
  f16x4 tv = *(const f16x4*)&t[(size_t)q * 4];
  float4 fv = ((const float4*)feat)[q];
  float4 sc = ((const float4*)scale)[c4];
  float4 sf = ((const float4*)shift)[c4];
  float4 o;
  o.x = fmaxf(sc.x * (float)tv[0] + sf.x + fv.x, 0.f);
  o.y = fmaxf(sc.y * (float)tv[1] + sf.y + fv.y, 0.f);
  o.z = fmaxf(sc.z * (float)tv[2] + sf.z + fv.z, 0.f);
  o.w = fmaxf(sc.w * (float)tv[3] + sf.w + fv.w, 0.f);
  ((float4*)out)[q] = o;
}

extern "C" void kernel_launch(void* const* d_in, const int* in_sizes, int n_in,
                              void* d_out, int out_size, void* d_ws, size_t ws_size,
                              hipStream_t stream) {
  const float* features = (const float*)d_in[0];
  const int* edges = (const int*)d_in[1];
  const float* W0 = (const float*)d_in[2];
  const float* b0 = (const float*)d_in[3];
  const float* W1 = (const float*)d_in[4];
  const float* b1 = (const float*)d_in[5];
  const float* gamma = (const float*)d_in[6];
  const float* beta = (const float*)d_in[7];
  float* out = (float*)d_out;

  char* ws = (char*)d_ws;
  size_t off = 0;
  auto alloc = [&](size_t bytes) -> void* {
    void* p = ws + off;
    off = (off + bytes + 255) & ~(size_t)255;
    return p;
  };
  int* deg = (int*)alloc((size_t)V_N * 4);
  int* csr_off = (int*)alloc((size_t)(V_N + 1) * 4);
  int* adj = (int*)alloc((size_t)2 * E_N * 4);
  int* adjell = (int*)alloc((size_t)V_N * 8 * 4);
  float* dinv = (float*)alloc((size_t)V_N * 4);
  float* degf = (float*)alloc((size_t)V_N * 4);
  int* csum = (int*)alloc(512 * 4);
  int* coff = (int*)alloc(512 * 4);
  float* stats = (float*)alloc(64 * 256 * 4);
  float* scale = (float*)alloc(128 * 4);
  float* shift = (float*)alloc(128 * 4);
  f16* y = (f16*)alloc((size_t)MPAD * 128 * 2);
  f16* xa = (f16*)alloc((size_t)MPAD * 128 * 2);
  f16* tbuf = (f16*)alloc((size_t)MPAD * 128 * 2);
  f16* Wcat = (f16*)alloc((size_t)3 * 128 * 256 * 2);

  // CSR + ELL8 + dinv/degf
  hipMemsetAsync(deg, 0, (size_t)V_N * 4, stream);
  k_count<<<(2 * E_N + 255) / 256, 256, 0, stream>>>(edges, deg);
  k_chunksum<<<NCHUNK, 256, 0, stream>>>(deg, csum);
  k_scanchunks<<<1, 512, 0, stream>>>(csum, coff);
  k_writeoff<<<NCHUNK, 256, 0, stream>>>(deg, coff, csr_off, dinv, degf);
  hipMemsetAsync(deg, 0, (size_t)V_N * 4, stream);
  k_fill<<<(E_N + 255) / 256, 256, 0, stream>>>(edges, csr_off, deg, adj, adjell);
  // after k_fill, deg (cursor) == degree again
  k_prepcast<<<384 + 12500, 256, 0, stream>>>(W0, W1, Wcat, features, y);

  for (int l = 0; l < 3; ++l) {
    if (l == 0)
      k_gather<0><<<6250, 256, 0, stream>>>(tbuf, y, xa, deg, csr_off, adjell, adj, scale, shift, stats);
    else
      k_gather<1><<<6250, 256, 0, stream>>>(tbuf, y, xa, deg, csr_off, adjell, adj, scale, shift, stats);
    k_gemm<<<MPAD / 64, 256, 0, stream>>>(y, xa, Wcat + (size_t)l * 128 * 256, b0 + l * D_N,
                                          b1 + l * D_N, dinv, degf, tbuf, stats);
    k_finalize<<<1, 128, 0, stream>>>(stats, gamma + l * D_N, beta + l * D_N, scale, shift);
  }
  k_final<<<12500, 256, 0, stream>>>(tbuf, features, scale, shift, out);
}